// Round 2
// baseline (636.487 us; speedup 1.0000x reference)
//
#include <hip/hip_runtime.h>

#define TT 365
#define NB 8     // 8 batches/block -> 512 blocks -> 2 independent blocks per CU
#define NTH 1024 // 16 waves: 0-7 = L2 (E) role, 8-15 = L1 (D) role
#define XLEN (NB * TT * 3)

typedef _Float16 halfx8 __attribute__((ext_vector_type(8)));
typedef float floatx4 __attribute__((ext_vector_type(4)));
typedef float floatx2 __attribute__((ext_vector_type(2)));

#define MMH(A, B, C) __builtin_amdgcn_mfma_f32_16x16x32_f16((A), (B), (C), 0, 0, 0)

// Gate rows PRE-SCALED: sigmoid rows by -log2e, g rows by -2log2e.
#define SGP -2.8853900817779268f
#define SGN  2.8853900817779268f
#define SS_  -1.4426950408889634f

static __device__ __forceinline__ float rcpf(float x) { return __builtin_amdgcn_rcpf(x); }
static __device__ __forceinline__ float ex2(float x)  { return __builtin_amdgcn_exp2f(x); }

#define LOADFRAG(SRC, SCALE, HI)                                               \
  do {                                                                         \
    _Pragma("unroll")                                                          \
    for (int jj = 0; jj < 8; ++jj) {                                           \
      (HI)[jj] = (_Float16)((SCALE) * (SRC)[jj]);                              \
    }                                                                          \
  } while (0)

// Packed tail, combined-rcp cell update (1 rcp for f & i*g paths):
//   c' = [c*(1+ei)(1+eg) + SGP*(1-eg)*(1+ef)] / [(1+ef)(1+ei)(1+eg)]
//   h  = (1-ec) / [(1+eo)(1+ec)],  ec = 2^c'  (c kept in SG-scaled domain)
#define PTAIL_CORE(PA, PB, CS2, HOUT)                                          \
  const floatx2 one_ = {1.0f, 1.0f};                                           \
  const floatx2 ei_ = {ex2((PA)[0]), ex2((PB)[0])};                            \
  const floatx2 ef_ = {ex2((PA)[1]), ex2((PB)[1])};                            \
  const floatx2 eg_ = {ex2((PA)[2]), ex2((PB)[2])};                            \
  const floatx2 eo_ = {ex2((PA)[3]), ex2((PB)[3])};                            \
  const floatx2 sgn2_ = {SGN, SGN};                                            \
  const floatx2 sgp2_ = {SGP, SGP};                                            \
  const floatx2 fd_ = one_ + ef_;                                              \
  const floatx2 P1_ = (one_ + ei_) * (one_ + eg_);                             \
  const floatx2 Dp_ = P1_ * fd_;                                               \
  const floatx2 R_  = {rcpf(Dp_.x), rcpf(Dp_.y)};                              \
  const floatx2 T_  = (sgn2_ * eg_ + sgp2_) * fd_;                             \
  (CS2) = ((CS2) * P1_ + T_) * R_;                                             \
  (CS2).x = fminf((CS2).x, 60.0f);                                             \
  (CS2).y = fminf((CS2).y, 60.0f);                                             \
  const floatx2 ec_ = {ex2((CS2).x), ex2((CS2).y)};                            \
  const floatx2 P2_ = (one_ + eo_) * (one_ + ec_);                             \
  const floatx2 R2_ = {rcpf(P2_.x), rcpf(P2_.y)};                              \
  const floatx2 HOUT = (one_ - ec_) * R2_;

// pack both h (adjacent units) into one b32 LDS write
#define PTAIL(PA, PB, CS2, ZW32, WIDX)                                         \
  do {                                                                         \
    PTAIL_CORE(PA, PB, CS2, hv_)                                               \
    (ZW32)[WIDX] =                                                             \
        __builtin_bit_cast(unsigned, __builtin_amdgcn_cvt_pkrtz(hv_.x, hv_.y)); \
  } while (0)

__global__ __launch_bounds__(NTH)
__attribute__((amdgpu_waves_per_eu(8, 8)))
void lstm2_mfma13(
    const float* __restrict__ x,
    const float* __restrict__ w_ih0, const float* __restrict__ w_hh0,
    const float* __restrict__ b_ih0, const float* __restrict__ b_hh0,
    const float* __restrict__ w_ih1, const float* __restrict__ w_hh1,
    const float* __restrict__ b_ih1, const float* __restrict__ b_hh1,
    float* __restrict__ out)
{
  __shared__ __align__(16) unsigned short Z[2][2048];  // fp16 h: [buf][kt][lane][8] (cols 8-15 mirror 0-7)
  __shared__ __align__(16) float xh[TT * NB * 4];      // x re-laid: [t][b][4] (pad unused)

  const int tid  = threadIdx.x;
  const int lane = tid & 63;
  const int wv   = tid >> 6;
  const int n15  = lane & 15;
  const int quad = lane >> 4;
  const int bbase = blockIdx.x * NB;
  const float sA = ((n15 & 3) == 2) ? SGP : SS_;

  // stage x -> [t][b][4] layout (coalesced global reads, scattered LDS writes)
  {
    const float* xg = x + (size_t)bbase * (TT * 3);
    for (int i = tid; i < XLEN; i += NTH) {
      const int b = i / 1095;
      const int rem = i - b * 1095;
      const int t = rem / 3;
      const int c = rem - 3 * t;
      xh[(t * NB + b) * 4 + c] = xg[i];
    }
    for (int i = tid; i < 2048; i += NTH) { Z[0][i] = 0; Z[1][i] = 0; }
  }
  unsigned short* const Zb0 = &Z[0][0];
  unsigned short* const Zb1 = &Z[1][0];
  __syncthreads();   // barrier #1

  // Adjacent-unit retiling: wave w, tile A -> units 8w+2q (q=quad), tile B -> +1.
  // Thread's two h values are units j0=8w+2q, j1=j0+1 -> one packed b32 write.
  // MFMA batch columns 8..15 duplicate columns 0..7 (NB=8): harmless, not stored.

  if (wv < 8) {
    // ================= E role: layer-2 GEMM + combine2 =================
    const int w = wv;
    halfx8 a2[2][4];
    floatx4 b1v[2];
    #pragma unroll
    for (int tt = 0; tt < 2; ++tt) {
      const int arow = (n15 & 3) * 64 + 8 * w + 2 * (n15 >> 2) + tt;
      #pragma unroll
      for (int kt = 0; kt < 4; ++kt) {
        const int k0 = kt * 32 + quad * 8;
        const float* src = (k0 < 64) ? (w_ih1 + arow * 64 + k0)
                                     : (w_hh1 + arow * 64 + (k0 - 64));
        LOADFRAG(src, sA, a2[tt][kt]);
      }
      #pragma unroll
      for (int r = 0; r < 4; ++r) {
        const int crow = r * 64 + 8 * w + 2 * quad + tt;
        const float sC = (r == 2) ? SGP : SS_;
        b1v[tt][r] = sC * (b_ih1[crow] + b_hh1[crow]);
      }
    }
    const int j0 = 8 * w + 2 * quad;
    const int widx = 512 + (w >> 2) * 256 + (w & 3) * 64 + n15 * 4 + quad;
    floatx2 c2v = {0.f, 0.f};
    const halfx8* const Z0r = (const halfx8*)Zb0 + lane;
    const halfx8* const Z1r = (const halfx8*)Zb1 + lane;

    __syncthreads();   // barrier #2 (matches D prologue barrier)

#define ESTEP(ZRP, ZW32)                                                       \
    do {                                                                       \
      const halfx8 bh0 = (ZRP)[0],   bh1 = (ZRP)[64];                          \
      const halfx8 bh2 = (ZRP)[128], bh3 = (ZRP)[192];                         \
      floatx4 e0 = b1v[0], e1 = b1v[1];                                        \
      e0 = MMH(a2[0][0], bh0, e0); e0 = MMH(a2[0][1], bh1, e0);                \
      e0 = MMH(a2[0][2], bh2, e0); e0 = MMH(a2[0][3], bh3, e0);                \
      e1 = MMH(a2[1][0], bh0, e1); e1 = MMH(a2[1][1], bh1, e1);                \
      e1 = MMH(a2[1][2], bh2, e1); e1 = MMH(a2[1][3], bh3, e1);                \
      PTAIL(e0, e1, c2v, ZW32, widx);                                          \
      __syncthreads();                                                         \
    } while (0)

    for (int it = 0; it < 182; ++it) {
      ESTEP(Z0r, (unsigned*)Zb1);
      ESTEP(Z1r, (unsigned*)Zb0);
    }

    // peel t=364: gates2 -> h2(364) -> out (units j0, j0+1 adjacent)
    {
      const halfx8 bh0 = Z0r[0],   bh1 = Z0r[64];
      const halfx8 bh2 = Z0r[128], bh3 = Z0r[192];
      floatx4 e0 = b1v[0], e1 = b1v[1];
      e0 = MMH(a2[0][0], bh0, e0); e0 = MMH(a2[0][1], bh1, e0);
      e0 = MMH(a2[0][2], bh2, e0); e0 = MMH(a2[0][3], bh3, e0);
      e1 = MMH(a2[1][0], bh0, e1); e1 = MMH(a2[1][1], bh1, e1);
      e1 = MMH(a2[1][2], bh2, e1); e1 = MMH(a2[1][3], bh3, e1);
      PTAIL_CORE(e0, e1, c2v, hv_)
      if (n15 < NB) {
        *(floatx2*)(out + (size_t)(bbase + n15) * 64 + j0) = hv_;
      }
    }
  } else {
    // ================= D role: layer-1 GEMM + combine1 =================
    const int u = wv - 8;
    halfx8 a1[2][2];
    floatx4 wiX[2], wiY[2], wiZ[2], b0v[2];
    #pragma unroll
    for (int tt = 0; tt < 2; ++tt) {
      const int arow = (n15 & 3) * 64 + 8 * u + 2 * (n15 >> 2) + tt;
      #pragma unroll
      for (int kt = 0; kt < 2; ++kt) {
        const float* src = w_hh0 + arow * 64 + kt * 32 + quad * 8;
        LOADFRAG(src, sA, a1[tt][kt]);
      }
      #pragma unroll
      for (int r = 0; r < 4; ++r) {
        const int crow = r * 64 + 8 * u + 2 * quad + tt;
        const float sC = (r == 2) ? SGP : SS_;
        wiX[tt][r] = sC * w_ih0[crow * 3 + 0];
        wiY[tt][r] = sC * w_ih0[crow * 3 + 1];
        wiZ[tt][r] = sC * w_ih0[crow * 3 + 2];
        b0v[tt][r] = sC * (b_ih0[crow] + b_hh0[crow]);
      }
    }
    const int widx = (u >> 2) * 256 + (u & 3) * 64 + n15 * 4 + quad;  // h1 region
    floatx2 c1v = {0.f, 0.f};
    const halfx8* const Z0r = (const halfx8*)Zb0 + lane;
    const halfx8* const Z1r = (const halfx8*)Zb1 + lane;
    const int bsl = (n15 & (NB - 1)) * 4;   // duplicate batch for lanes n15>=NB

    // prologue: h1(0) from x(0) only -> Zb0
    {
      const floatx4 xv = *(const floatx4*)(xh + bsl);
      const floatx4 s0 = {xv[0], xv[0], xv[0], xv[0]};
      const floatx4 s1 = {xv[1], xv[1], xv[1], xv[1]};
      const floatx4 s2 = {xv[2], xv[2], xv[2], xv[2]};
      floatx4 d0 = __builtin_elementwise_fma(wiX[0], s0,
                     __builtin_elementwise_fma(wiY[0], s1,
                       __builtin_elementwise_fma(wiZ[0], s2, b0v[0])));
      floatx4 d1 = __builtin_elementwise_fma(wiX[1], s0,
                     __builtin_elementwise_fma(wiY[1], s1,
                       __builtin_elementwise_fma(wiZ[1], s2, b0v[1])));
      PTAIL(d0, d1, c1v, (unsigned*)Zb0, widx);   // c1v=0 -> f-term vanishes
    }
    __syncthreads();   // barrier #2

    const float* xp = xh + NB * 4 + bsl;   // x(t+1), one b128 per step

#define DSTEP(ZRP, ZW32)                                                       \
    do {                                                                       \
      const halfx8 bh0 = (ZRP)[0], bh1 = (ZRP)[64];                            \
      const floatx4 xv = *(const floatx4*)xp;                                  \
      const floatx4 s0 = {xv[0], xv[0], xv[0], xv[0]};                         \
      const floatx4 s1 = {xv[1], xv[1], xv[1], xv[1]};                         \
      const floatx4 s2 = {xv[2], xv[2], xv[2], xv[2]};                         \
      floatx4 d0 = __builtin_elementwise_fma(wiX[0], s0,                       \
                     __builtin_elementwise_fma(wiY[0], s1,                     \
                       __builtin_elementwise_fma(wiZ[0], s2, b0v[0])));        \
      floatx4 d1 = __builtin_elementwise_fma(wiX[1], s0,                       \
                     __builtin_elementwise_fma(wiY[1], s1,                     \
                       __builtin_elementwise_fma(wiZ[1], s2, b0v[1])));        \
      d0 = MMH(a1[0][0], bh0, d0); d0 = MMH(a1[0][1], bh1, d0);                \
      d1 = MMH(a1[1][0], bh0, d1); d1 = MMH(a1[1][1], bh1, d1);                \
      PTAIL(d0, d1, c1v, ZW32, widx);                                          \
      xp += NB * 4;                                                            \
      __syncthreads();                                                         \
    } while (0)

    for (int it = 0; it < 182; ++it) {
      DSTEP(Z0r, (unsigned*)Zb1);
      DSTEP(Z1r, (unsigned*)Zb0);
    }
    // peel t=364: nothing for D
  }
}

extern "C" void kernel_launch(void* const* d_in, const int* in_sizes, int n_in,
                              void* d_out, int out_size, void* d_ws, size_t ws_size,
                              hipStream_t stream) {
  const float* x     = (const float*)d_in[0];
  const float* w_ih0 = (const float*)d_in[1];
  const float* w_hh0 = (const float*)d_in[2];
  const float* b_ih0 = (const float*)d_in[3];
  const float* b_hh0 = (const float*)d_in[4];
  const float* w_ih1 = (const float*)d_in[5];
  const float* w_hh1 = (const float*)d_in[6];
  const float* b_ih1 = (const float*)d_in[7];
  const float* b_hh1 = (const float*)d_in[8];
  float* out = (float*)d_out;

  const int B = in_sizes[0] / (TT * 3);   // 4096
  const int grid = B / NB;                // 512 blocks -> 2 per CU

  lstm2_mfma13<<<dim3(grid), dim3(NTH), 0, stream>>>(
      x, w_ih0, w_hh0, b_ih0, b_hh0, w_ih1, w_hh1, b_ih1, b_hh1, out);
}

// Round 3
// 558.712 us; speedup vs baseline: 1.1392x; 1.1392x over previous
//
#include <hip/hip_runtime.h>

#define TT 365
#define NB 8     // 8 batches/block -> 512 blocks -> 2 independent blocks per CU
#define NTH 1024 // 16 waves: 0-7 = L2 (E) role, 8-15 = L1 (D) role
#define XLEN (NB * TT * 3)

typedef _Float16 halfx8 __attribute__((ext_vector_type(8)));
typedef float floatx4 __attribute__((ext_vector_type(4)));
typedef float floatx2 __attribute__((ext_vector_type(2)));

#define MMH(A, B, C) __builtin_amdgcn_mfma_f32_16x16x32_f16((A), (B), (C), 0, 0, 0)

// Gate rows PRE-SCALED: sigmoid rows by -log2e, g rows by -2log2e.
#define SGP -2.8853900817779268f
#define SGN  2.8853900817779268f
#define SS_  -1.4426950408889634f

static __device__ __forceinline__ float rcpf(float x) { return __builtin_amdgcn_rcpf(x); }
static __device__ __forceinline__ float ex2(float x)  { return __builtin_amdgcn_exp2f(x); }

#define LOADFRAG(SRC, SCALE, HI)                                               \
  do {                                                                         \
    _Pragma("unroll")                                                          \
    for (int jj = 0; jj < 8; ++jj) {                                           \
      (HI)[jj] = (_Float16)((SCALE) * (SRC)[jj]);                              \
    }                                                                          \
  } while (0)

// Packed tail, combined-rcp cell update (1 rcp for f & i*g paths):
//   c' = [c*(1+ei)(1+eg) + SGP*(1-eg)*(1+ef)] / [(1+ef)(1+ei)(1+eg)]
//   h  = (1-ec) / [(1+eo)(1+ec)],  ec = 2^c'  (c kept in SG-scaled domain)
#define PTAIL_CORE(PA, PB, CS2, HOUT)                                          \
  const floatx2 one_ = {1.0f, 1.0f};                                           \
  const floatx2 ei_ = {ex2((PA)[0]), ex2((PB)[0])};                            \
  const floatx2 ef_ = {ex2((PA)[1]), ex2((PB)[1])};                            \
  const floatx2 eg_ = {ex2((PA)[2]), ex2((PB)[2])};                            \
  const floatx2 eo_ = {ex2((PA)[3]), ex2((PB)[3])};                            \
  const floatx2 sgn2_ = {SGN, SGN};                                            \
  const floatx2 sgp2_ = {SGP, SGP};                                            \
  const floatx2 fd_ = one_ + ef_;                                              \
  const floatx2 P1_ = (one_ + ei_) * (one_ + eg_);                             \
  const floatx2 Dp_ = P1_ * fd_;                                               \
  const floatx2 R_  = {rcpf(Dp_.x), rcpf(Dp_.y)};                              \
  const floatx2 T_  = (sgn2_ * eg_ + sgp2_) * fd_;                             \
  (CS2) = ((CS2) * P1_ + T_) * R_;                                             \
  (CS2).x = fminf((CS2).x, 60.0f);                                             \
  (CS2).y = fminf((CS2).y, 60.0f);                                             \
  const floatx2 ec_ = {ex2((CS2).x), ex2((CS2).y)};                            \
  const floatx2 P2_ = (one_ + eo_) * (one_ + ec_);                             \
  const floatx2 R2_ = {rcpf(P2_.x), rcpf(P2_.y)};                              \
  const floatx2 HOUT = (one_ - ec_) * R2_;

// pack both h (adjacent units) into one b32 LDS write
#define PTAIL(PA, PB, CS2, ZW32, WIDX)                                         \
  do {                                                                         \
    PTAIL_CORE(PA, PB, CS2, hv_)                                               \
    (ZW32)[WIDX] =                                                             \
        __builtin_bit_cast(unsigned, __builtin_amdgcn_cvt_pkrtz(hv_.x, hv_.y)); \
  } while (0)

__global__ __launch_bounds__(NTH)
__attribute__((amdgpu_waves_per_eu(4, 4)))   // known-good 52-VGPR codegen; runtime can still co-schedule 2 blocks
void lstm2_mfma14(
    const float* __restrict__ x,
    const float* __restrict__ w_ih0, const float* __restrict__ w_hh0,
    const float* __restrict__ b_ih0, const float* __restrict__ b_hh0,
    const float* __restrict__ w_ih1, const float* __restrict__ w_hh1,
    const float* __restrict__ b_ih1, const float* __restrict__ b_hh1,
    float* __restrict__ out)
{
  __shared__ __align__(16) unsigned short Z[2][2048];  // fp16 h: [buf][kt][lane][8] (cols 8-15 mirror 0-7)
  __shared__ __align__(16) float xh[TT * NB * 4];      // x re-laid: [t][b][4] (pad unused)

  const int tid  = threadIdx.x;
  const int lane = tid & 63;
  const int wv   = tid >> 6;
  const int n15  = lane & 15;
  const int quad = lane >> 4;
  const int bbase = blockIdx.x * NB;
  const float sA = ((n15 & 3) == 2) ? SGP : SS_;

  // stage x -> [t][b][4] layout (coalesced global reads, scattered LDS writes)
  {
    const float* xg = x + (size_t)bbase * (TT * 3);
    for (int i = tid; i < XLEN; i += NTH) {
      const int b = i / 1095;
      const int rem = i - b * 1095;
      const int t = rem / 3;
      const int c = rem - 3 * t;
      xh[(t * NB + b) * 4 + c] = xg[i];
    }
    for (int i = tid; i < 2048; i += NTH) { Z[0][i] = 0; Z[1][i] = 0; }
  }
  unsigned short* const Zb0 = &Z[0][0];
  unsigned short* const Zb1 = &Z[1][0];
  __syncthreads();   // barrier #1

  // Adjacent-unit retiling: wave w, tile A -> units 8w+2q (q=quad), tile B -> +1.
  // Thread's two h values are units j0=8w+2q, j1=j0+1 -> one packed b32 write.
  // MFMA batch columns 8..15 duplicate columns 0..7 (NB=8): harmless, not stored.

  if (wv < 8) {
    // ================= E role: layer-2 GEMM + combine2 =================
    const int w = wv;
    halfx8 a2[2][4];
    floatx4 b1v[2];
    #pragma unroll
    for (int tt = 0; tt < 2; ++tt) {
      const int arow = (n15 & 3) * 64 + 8 * w + 2 * (n15 >> 2) + tt;
      #pragma unroll
      for (int kt = 0; kt < 4; ++kt) {
        const int k0 = kt * 32 + quad * 8;
        const float* src = (k0 < 64) ? (w_ih1 + arow * 64 + k0)
                                     : (w_hh1 + arow * 64 + (k0 - 64));
        LOADFRAG(src, sA, a2[tt][kt]);
      }
      #pragma unroll
      for (int r = 0; r < 4; ++r) {
        const int crow = r * 64 + 8 * w + 2 * quad + tt;
        const float sC = (r == 2) ? SGP : SS_;
        b1v[tt][r] = sC * (b_ih1[crow] + b_hh1[crow]);
      }
    }
    const int j0 = 8 * w + 2 * quad;
    const int widx = 512 + (w >> 2) * 256 + (w & 3) * 64 + n15 * 4 + quad;
    floatx2 c2v = {0.f, 0.f};
    const halfx8* const Z0r = (const halfx8*)Zb0 + lane;
    const halfx8* const Z1r = (const halfx8*)Zb1 + lane;

    __syncthreads();   // barrier #2 (matches D prologue barrier)

#define ESTEP(ZRP, ZW32)                                                       \
    do {                                                                       \
      const halfx8 bh0 = (ZRP)[0],   bh1 = (ZRP)[64];                          \
      const halfx8 bh2 = (ZRP)[128], bh3 = (ZRP)[192];                         \
      floatx4 e0 = b1v[0], e1 = b1v[1];                                        \
      e0 = MMH(a2[0][0], bh0, e0); e0 = MMH(a2[0][1], bh1, e0);                \
      e0 = MMH(a2[0][2], bh2, e0); e0 = MMH(a2[0][3], bh3, e0);                \
      e1 = MMH(a2[1][0], bh0, e1); e1 = MMH(a2[1][1], bh1, e1);                \
      e1 = MMH(a2[1][2], bh2, e1); e1 = MMH(a2[1][3], bh3, e1);                \
      PTAIL(e0, e1, c2v, ZW32, widx);                                          \
      __syncthreads();                                                         \
    } while (0)

    for (int it = 0; it < 182; ++it) {
      ESTEP(Z0r, (unsigned*)Zb1);
      ESTEP(Z1r, (unsigned*)Zb0);
    }

    // peel t=364: gates2 -> h2(364) -> out (units j0, j0+1 adjacent)
    {
      const halfx8 bh0 = Z0r[0],   bh1 = Z0r[64];
      const halfx8 bh2 = Z0r[128], bh3 = Z0r[192];
      floatx4 e0 = b1v[0], e1 = b1v[1];
      e0 = MMH(a2[0][0], bh0, e0); e0 = MMH(a2[0][1], bh1, e0);
      e0 = MMH(a2[0][2], bh2, e0); e0 = MMH(a2[0][3], bh3, e0);
      e1 = MMH(a2[1][0], bh0, e1); e1 = MMH(a2[1][1], bh1, e1);
      e1 = MMH(a2[1][2], bh2, e1); e1 = MMH(a2[1][3], bh3, e1);
      PTAIL_CORE(e0, e1, c2v, hv_)
      if (n15 < NB) {
        *(floatx2*)(out + (size_t)(bbase + n15) * 64 + j0) = hv_;
      }
    }
  } else {
    // ================= D role: layer-1 GEMM + combine1 =================
    const int u = wv - 8;
    halfx8 a1[2][2];
    floatx4 wiX[2], wiY[2], wiZ[2], b0v[2];
    #pragma unroll
    for (int tt = 0; tt < 2; ++tt) {
      const int arow = (n15 & 3) * 64 + 8 * u + 2 * (n15 >> 2) + tt;
      #pragma unroll
      for (int kt = 0; kt < 2; ++kt) {
        const float* src = w_hh0 + arow * 64 + kt * 32 + quad * 8;
        LOADFRAG(src, sA, a1[tt][kt]);
      }
      #pragma unroll
      for (int r = 0; r < 4; ++r) {
        const int crow = r * 64 + 8 * u + 2 * quad + tt;
        const float sC = (r == 2) ? SGP : SS_;
        wiX[tt][r] = sC * w_ih0[crow * 3 + 0];
        wiY[tt][r] = sC * w_ih0[crow * 3 + 1];
        wiZ[tt][r] = sC * w_ih0[crow * 3 + 2];
        b0v[tt][r] = sC * (b_ih0[crow] + b_hh0[crow]);
      }
    }
    const int widx = (u >> 2) * 256 + (u & 3) * 64 + n15 * 4 + quad;  // h1 region
    floatx2 c1v = {0.f, 0.f};
    const halfx8* const Z0r = (const halfx8*)Zb0 + lane;
    const halfx8* const Z1r = (const halfx8*)Zb1 + lane;
    const int bsl = (n15 & (NB - 1)) * 4;   // duplicate batch for lanes n15>=NB

    // prologue: h1(0) from x(0) only -> Zb0
    {
      const floatx4 xv = *(const floatx4*)(xh + bsl);
      const floatx4 s0 = {xv[0], xv[0], xv[0], xv[0]};
      const floatx4 s1 = {xv[1], xv[1], xv[1], xv[1]};
      const floatx4 s2 = {xv[2], xv[2], xv[2], xv[2]};
      floatx4 d0 = __builtin_elementwise_fma(wiX[0], s0,
                     __builtin_elementwise_fma(wiY[0], s1,
                       __builtin_elementwise_fma(wiZ[0], s2, b0v[0])));
      floatx4 d1 = __builtin_elementwise_fma(wiX[1], s0,
                     __builtin_elementwise_fma(wiY[1], s1,
                       __builtin_elementwise_fma(wiZ[1], s2, b0v[1])));
      PTAIL(d0, d1, c1v, (unsigned*)Zb0, widx);   // c1v=0 -> f-term vanishes
    }
    __syncthreads();   // barrier #2

    const float* xp = xh + NB * 4 + bsl;   // x(t+1), one b128 per step

#define DSTEP(ZRP, ZW32)                                                       \
    do {                                                                       \
      const halfx8 bh0 = (ZRP)[0], bh1 = (ZRP)[64];                            \
      const floatx4 xv = *(const floatx4*)xp;                                  \
      const floatx4 s0 = {xv[0], xv[0], xv[0], xv[0]};                         \
      const floatx4 s1 = {xv[1], xv[1], xv[1], xv[1]};                         \
      const floatx4 s2 = {xv[2], xv[2], xv[2], xv[2]};                         \
      floatx4 d0 = __builtin_elementwise_fma(wiX[0], s0,                       \
                     __builtin_elementwise_fma(wiY[0], s1,                     \
                       __builtin_elementwise_fma(wiZ[0], s2, b0v[0])));        \
      floatx4 d1 = __builtin_elementwise_fma(wiX[1], s0,                       \
                     __builtin_elementwise_fma(wiY[1], s1,                     \
                       __builtin_elementwise_fma(wiZ[1], s2, b0v[1])));        \
      d0 = MMH(a1[0][0], bh0, d0); d0 = MMH(a1[0][1], bh1, d0);                \
      d1 = MMH(a1[1][0], bh0, d1); d1 = MMH(a1[1][1], bh1, d1);                \
      PTAIL(d0, d1, c1v, ZW32, widx);                                          \
      xp += NB * 4;                                                            \
      __syncthreads();                                                         \
    } while (0)

    for (int it = 0; it < 182; ++it) {
      DSTEP(Z0r, (unsigned*)Zb1);
      DSTEP(Z1r, (unsigned*)Zb0);
    }
    // peel t=364: nothing for D
  }
}

extern "C" void kernel_launch(void* const* d_in, const int* in_sizes, int n_in,
                              void* d_out, int out_size, void* d_ws, size_t ws_size,
                              hipStream_t stream) {
  const float* x     = (const float*)d_in[0];
  const float* w_ih0 = (const float*)d_in[1];
  const float* w_hh0 = (const float*)d_in[2];
  const float* b_ih0 = (const float*)d_in[3];
  const float* b_hh0 = (const float*)d_in[4];
  const float* w_ih1 = (const float*)d_in[5];
  const float* w_hh1 = (const float*)d_in[6];
  const float* b_ih1 = (const float*)d_in[7];
  const float* b_hh1 = (const float*)d_in[8];
  float* out = (float*)d_out;

  const int B = in_sizes[0] / (TT * 3);   // 4096
  const int grid = B / NB;                // 512 blocks -> 2 per CU

  lstm2_mfma14<<<dim3(grid), dim3(NTH), 0, stream>>>(
      x, w_ih0, w_hh0, b_ih0, b_hh0, w_ih1, w_hh1, b_ih1, b_hh1, out);
}

// Round 4
// 538.865 us; speedup vs baseline: 1.1812x; 1.0368x over previous
//
#include <hip/hip_runtime.h>

#define TT 365
#define NB 8     // 8 batches/block -> 512 blocks -> 2 independent blocks per CU
#define NTH 1024 // 16 waves: 0-7 = L2 (E) role, 8-15 = L1 (D) role
#define XLEN (NB * TT * 3)

typedef _Float16 halfx8 __attribute__((ext_vector_type(8)));
typedef float floatx4 __attribute__((ext_vector_type(4)));
typedef float floatx2 __attribute__((ext_vector_type(2)));

#define MMH(A, B, C) __builtin_amdgcn_mfma_f32_16x16x32_f16((A), (B), (C), 0, 0, 0)

// Gate rows PRE-SCALED: sigmoid rows by -log2e, g rows by -2log2e.
#define SGP -2.8853900817779268f
#define SGN  2.8853900817779268f
#define SS_  -1.4426950408889634f

static __device__ __forceinline__ float rcpf(float x) { return __builtin_amdgcn_rcpf(x); }
static __device__ __forceinline__ float ex2(float x)  { return __builtin_amdgcn_exp2f(x); }

#define LOADFRAG(SRC, SCALE, HI)                                               \
  do {                                                                         \
    _Pragma("unroll")                                                          \
    for (int jj = 0; jj < 8; ++jj) {                                           \
      (HI)[jj] = (_Float16)((SCALE) * (SRC)[jj]);                              \
    }                                                                          \
  } while (0)

// Packed tail, combined-rcp cell update (1 rcp for f & i*g paths):
//   c' = [c*(1+ei)(1+eg) + SGP*(1-eg)*(1+ef)] / [(1+ef)(1+ei)(1+eg)]
//   h  = (1-ec) / [(1+eo)(1+ec)],  ec = 2^c'  (c kept in SG-scaled domain)
#define PTAIL_CORE(PA, PB, CS2, HOUT)                                          \
  const floatx2 one_ = {1.0f, 1.0f};                                           \
  const floatx2 ei_ = {ex2((PA)[0]), ex2((PB)[0])};                            \
  const floatx2 ef_ = {ex2((PA)[1]), ex2((PB)[1])};                            \
  const floatx2 eg_ = {ex2((PA)[2]), ex2((PB)[2])};                            \
  const floatx2 eo_ = {ex2((PA)[3]), ex2((PB)[3])};                            \
  const floatx2 sgn2_ = {SGN, SGN};                                            \
  const floatx2 sgp2_ = {SGP, SGP};                                            \
  const floatx2 fd_ = one_ + ef_;                                              \
  const floatx2 P1_ = (one_ + ei_) * (one_ + eg_);                             \
  const floatx2 Dp_ = P1_ * fd_;                                               \
  const floatx2 R_  = {rcpf(Dp_.x), rcpf(Dp_.y)};                              \
  const floatx2 T_  = (sgn2_ * eg_ + sgp2_) * fd_;                             \
  (CS2) = ((CS2) * P1_ + T_) * R_;                                             \
  (CS2).x = fminf((CS2).x, 60.0f);                                             \
  (CS2).y = fminf((CS2).y, 60.0f);                                             \
  const floatx2 ec_ = {ex2((CS2).x), ex2((CS2).y)};                            \
  const floatx2 P2_ = (one_ + eo_) * (one_ + ec_);                             \
  const floatx2 R2_ = {rcpf(P2_.x), rcpf(P2_.y)};                              \
  const floatx2 HOUT = (one_ - ec_) * R2_;

// pack both h (adjacent units) into one b32 LDS write
#define PTAIL(PA, PB, CS2, ZW32, WIDX)                                         \
  do {                                                                         \
    PTAIL_CORE(PA, PB, CS2, hv_)                                               \
    (ZW32)[WIDX] =                                                             \
        __builtin_bit_cast(unsigned, __builtin_amdgcn_cvt_pkrtz(hv_.x, hv_.y)); \
  } while (0)

__global__ __launch_bounds__(NTH)
__attribute__((amdgpu_waves_per_eu(4, 8)))   // min=4 keeps 52-VGPR codegen; max=8 lifts the residency clamp
void lstm2_mfma15(
    const float* __restrict__ x,
    const float* __restrict__ w_ih0, const float* __restrict__ w_hh0,
    const float* __restrict__ b_ih0, const float* __restrict__ b_hh0,
    const float* __restrict__ w_ih1, const float* __restrict__ w_hh1,
    const float* __restrict__ b_ih1, const float* __restrict__ b_hh1,
    float* __restrict__ out)
{
  __shared__ __align__(16) unsigned short Z[2][2048];  // fp16 h: [buf][kt][lane][8] (cols 8-15 mirror 0-7)
  __shared__ __align__(16) float xh[TT * NB * 4];      // x re-laid: [t][b][4] (pad unused)

  const int tid  = threadIdx.x;
  const int lane = tid & 63;
  const int wv   = tid >> 6;
  const int n15  = lane & 15;
  const int quad = lane >> 4;
  const int bbase = blockIdx.x * NB;
  const float sA = ((n15 & 3) == 2) ? SGP : SS_;

  // stage x -> [t][b][4] layout (coalesced global reads, scattered LDS writes)
  {
    const float* xg = x + (size_t)bbase * (TT * 3);
    for (int i = tid; i < XLEN; i += NTH) {
      const int b = i / 1095;
      const int rem = i - b * 1095;
      const int t = rem / 3;
      const int c = rem - 3 * t;
      xh[(t * NB + b) * 4 + c] = xg[i];
    }
    for (int i = tid; i < 2048; i += NTH) { Z[0][i] = 0; Z[1][i] = 0; }
  }
  unsigned short* const Zb0 = &Z[0][0];
  unsigned short* const Zb1 = &Z[1][0];
  __syncthreads();   // barrier #1

  // Adjacent-unit retiling: wave w, tile A -> units 8w+2q (q=quad), tile B -> +1.
  // Thread's two h values are units j0=8w+2q, j1=j0+1 -> one packed b32 write.
  // MFMA batch columns 8..15 duplicate columns 0..7 (NB=8): harmless, not stored.

  if (wv < 8) {
    // ================= E role: layer-2 GEMM + combine2 =================
    const int w = wv;
    halfx8 a2[2][4];
    floatx4 b1v[2];
    #pragma unroll
    for (int tt = 0; tt < 2; ++tt) {
      const int arow = (n15 & 3) * 64 + 8 * w + 2 * (n15 >> 2) + tt;
      #pragma unroll
      for (int kt = 0; kt < 4; ++kt) {
        const int k0 = kt * 32 + quad * 8;
        const float* src = (k0 < 64) ? (w_ih1 + arow * 64 + k0)
                                     : (w_hh1 + arow * 64 + (k0 - 64));
        LOADFRAG(src, sA, a2[tt][kt]);
      }
      #pragma unroll
      for (int r = 0; r < 4; ++r) {
        const int crow = r * 64 + 8 * w + 2 * quad + tt;
        const float sC = (r == 2) ? SGP : SS_;
        b1v[tt][r] = sC * (b_ih1[crow] + b_hh1[crow]);
      }
    }
    const int j0 = 8 * w + 2 * quad;
    const int widx = 512 + (w >> 2) * 256 + (w & 3) * 64 + n15 * 4 + quad;
    floatx2 c2v = {0.f, 0.f};
    const halfx8* const Z0r = (const halfx8*)Zb0 + lane;
    const halfx8* const Z1r = (const halfx8*)Zb1 + lane;

    __syncthreads();   // barrier #2 (matches D prologue barrier)

#define ESTEP(ZRP, ZW32)                                                       \
    do {                                                                       \
      const halfx8 bh0 = (ZRP)[0],   bh1 = (ZRP)[64];                          \
      const halfx8 bh2 = (ZRP)[128], bh3 = (ZRP)[192];                         \
      floatx4 e0 = b1v[0], e1 = b1v[1];                                        \
      e0 = MMH(a2[0][0], bh0, e0); e0 = MMH(a2[0][1], bh1, e0);                \
      e0 = MMH(a2[0][2], bh2, e0); e0 = MMH(a2[0][3], bh3, e0);                \
      e1 = MMH(a2[1][0], bh0, e1); e1 = MMH(a2[1][1], bh1, e1);                \
      e1 = MMH(a2[1][2], bh2, e1); e1 = MMH(a2[1][3], bh3, e1);                \
      PTAIL(e0, e1, c2v, ZW32, widx);                                          \
      __syncthreads();                                                         \
    } while (0)

    for (int it = 0; it < 182; ++it) {
      ESTEP(Z0r, (unsigned*)Zb1);
      ESTEP(Z1r, (unsigned*)Zb0);
    }

    // peel t=364: gates2 -> h2(364) -> out (units j0, j0+1 adjacent)
    {
      const halfx8 bh0 = Z0r[0],   bh1 = Z0r[64];
      const halfx8 bh2 = Z0r[128], bh3 = Z0r[192];
      floatx4 e0 = b1v[0], e1 = b1v[1];
      e0 = MMH(a2[0][0], bh0, e0); e0 = MMH(a2[0][1], bh1, e0);
      e0 = MMH(a2[0][2], bh2, e0); e0 = MMH(a2[0][3], bh3, e0);
      e1 = MMH(a2[1][0], bh0, e1); e1 = MMH(a2[1][1], bh1, e1);
      e1 = MMH(a2[1][2], bh2, e1); e1 = MMH(a2[1][3], bh3, e1);
      PTAIL_CORE(e0, e1, c2v, hv_)
      if (n15 < NB) {
        *(floatx2*)(out + (size_t)(bbase + n15) * 64 + j0) = hv_;
      }
    }
  } else {
    // ================= D role: layer-1 GEMM + combine1 =================
    const int u = wv - 8;
    halfx8 a1[2][2];
    floatx4 wiX[2], wiY[2], wiZ[2], b0v[2];
    #pragma unroll
    for (int tt = 0; tt < 2; ++tt) {
      const int arow = (n15 & 3) * 64 + 8 * u + 2 * (n15 >> 2) + tt;
      #pragma unroll
      for (int kt = 0; kt < 2; ++kt) {
        const float* src = w_hh0 + arow * 64 + kt * 32 + quad * 8;
        LOADFRAG(src, sA, a1[tt][kt]);
      }
      #pragma unroll
      for (int r = 0; r < 4; ++r) {
        const int crow = r * 64 + 8 * u + 2 * quad + tt;
        const float sC = (r == 2) ? SGP : SS_;
        wiX[tt][r] = sC * w_ih0[crow * 3 + 0];
        wiY[tt][r] = sC * w_ih0[crow * 3 + 1];
        wiZ[tt][r] = sC * w_ih0[crow * 3 + 2];
        b0v[tt][r] = sC * (b_ih0[crow] + b_hh0[crow]);
      }
    }
    const int widx = (u >> 2) * 256 + (u & 3) * 64 + n15 * 4 + quad;  // h1 region
    floatx2 c1v = {0.f, 0.f};
    const halfx8* const Z0r = (const halfx8*)Zb0 + lane;
    const halfx8* const Z1r = (const halfx8*)Zb1 + lane;
    const int bsl = (n15 & (NB - 1)) * 4;   // duplicate batch for lanes n15>=NB

    // prologue: h1(0) from x(0) only -> Zb0
    {
      const floatx4 xv = *(const floatx4*)(xh + bsl);
      const floatx4 s0 = {xv[0], xv[0], xv[0], xv[0]};
      const floatx4 s1 = {xv[1], xv[1], xv[1], xv[1]};
      const floatx4 s2 = {xv[2], xv[2], xv[2], xv[2]};
      floatx4 d0 = __builtin_elementwise_fma(wiX[0], s0,
                     __builtin_elementwise_fma(wiY[0], s1,
                       __builtin_elementwise_fma(wiZ[0], s2, b0v[0])));
      floatx4 d1 = __builtin_elementwise_fma(wiX[1], s0,
                     __builtin_elementwise_fma(wiY[1], s1,
                       __builtin_elementwise_fma(wiZ[1], s2, b0v[1])));
      PTAIL(d0, d1, c1v, (unsigned*)Zb0, widx);   // c1v=0 -> f-term vanishes
    }
    __syncthreads();   // barrier #2

    const float* xp = xh + NB * 4 + bsl;   // x(t+1), one b128 per step

#define DSTEP(ZRP, ZW32)                                                       \
    do {                                                                       \
      const halfx8 bh0 = (ZRP)[0], bh1 = (ZRP)[64];                            \
      const floatx4 xv = *(const floatx4*)xp;                                  \
      const floatx4 s0 = {xv[0], xv[0], xv[0], xv[0]};                         \
      const floatx4 s1 = {xv[1], xv[1], xv[1], xv[1]};                         \
      const floatx4 s2 = {xv[2], xv[2], xv[2], xv[2]};                         \
      floatx4 d0 = __builtin_elementwise_fma(wiX[0], s0,                       \
                     __builtin_elementwise_fma(wiY[0], s1,                     \
                       __builtin_elementwise_fma(wiZ[0], s2, b0v[0])));        \
      floatx4 d1 = __builtin_elementwise_fma(wiX[1], s0,                       \
                     __builtin_elementwise_fma(wiY[1], s1,                     \
                       __builtin_elementwise_fma(wiZ[1], s2, b0v[1])));        \
      d0 = MMH(a1[0][0], bh0, d0); d0 = MMH(a1[0][1], bh1, d0);                \
      d1 = MMH(a1[1][0], bh0, d1); d1 = MMH(a1[1][1], bh1, d1);                \
      PTAIL(d0, d1, c1v, ZW32, widx);                                          \
      xp += NB * 4;                                                            \
      __syncthreads();                                                         \
    } while (0)

    for (int it = 0; it < 182; ++it) {
      DSTEP(Z0r, (unsigned*)Zb1);
      DSTEP(Z1r, (unsigned*)Zb0);
    }
    // peel t=364: nothing for D
  }
}

extern "C" void kernel_launch(void* const* d_in, const int* in_sizes, int n_in,
                              void* d_out, int out_size, void* d_ws, size_t ws_size,
                              hipStream_t stream) {
  const float* x     = (const float*)d_in[0];
  const float* w_ih0 = (const float*)d_in[1];
  const float* w_hh0 = (const float*)d_in[2];
  const float* b_ih0 = (const float*)d_in[3];
  const float* b_hh0 = (const float*)d_in[4];
  const float* w_ih1 = (const float*)d_in[5];
  const float* w_hh1 = (const float*)d_in[6];
  const float* b_ih1 = (const float*)d_in[7];
  const float* b_hh1 = (const float*)d_in[8];
  float* out = (float*)d_out;

  const int B = in_sizes[0] / (TT * 3);   // 4096
  const int grid = B / NB;                // 512 blocks -> 2 per CU

  lstm2_mfma15<<<dim3(grid), dim3(NTH), 0, stream>>>(
      x, w_ih0, w_hh0, b_ih0, b_hh0, w_ih1, w_hh1, b_ih1, b_hh1, out);
}

// Round 5
// 315.314 us; speedup vs baseline: 2.0186x; 1.7090x over previous
//
#include <hip/hip_runtime.h>

#define TT 365
#define NB 16
#define NTH 1024   // 16 waves: 0-7 = L2 (E) role, 8-15 = L1 (D) role
#define XLEN (NB * TT * 3)

typedef _Float16 halfx8 __attribute__((ext_vector_type(8)));
typedef float floatx4 __attribute__((ext_vector_type(4)));
typedef float floatx2 __attribute__((ext_vector_type(2)));

#define MMH(A, B, C) __builtin_amdgcn_mfma_f32_16x16x32_f16((A), (B), (C), 0, 0, 0)

// Gate rows PRE-SCALED: sigmoid rows by -log2e, g rows by -2log2e.
#define SGP -2.8853900817779268f
#define SGN  2.8853900817779268f
#define SS_  -1.4426950408889634f

static __device__ __forceinline__ float rcpf(float x) { return __builtin_amdgcn_rcpf(x); }
static __device__ __forceinline__ float ex2(float x)  { return __builtin_amdgcn_exp2f(x); }

#define LOADFRAG(SRC, SCALE, HI)                                               \
  do {                                                                         \
    _Pragma("unroll")                                                          \
    for (int jj = 0; jj < 8; ++jj) {                                           \
      (HI)[jj] = (_Float16)((SCALE) * (SRC)[jj]);                              \
    }                                                                          \
  } while (0)

// Packed tail, combined-rcp cell update (1 rcp for f & i*g paths):
//   c' = [c*(1+ei)(1+eg) + SGP*(1-eg)*(1+ef)] / [(1+ef)(1+ei)(1+eg)]
//   h  = (1-ec) / [(1+eo)(1+ec)],  ec = 2^c'  (c kept in SG-scaled domain)
#define PTAIL_CORE(PA, PB, CS2, HOUT)                                          \
  const floatx2 one_ = {1.0f, 1.0f};                                           \
  const floatx2 ei_ = {ex2((PA)[0]), ex2((PB)[0])};                            \
  const floatx2 ef_ = {ex2((PA)[1]), ex2((PB)[1])};                            \
  const floatx2 eg_ = {ex2((PA)[2]), ex2((PB)[2])};                            \
  const floatx2 eo_ = {ex2((PA)[3]), ex2((PB)[3])};                            \
  const floatx2 sgn2_ = {SGN, SGN};                                            \
  const floatx2 sgp2_ = {SGP, SGP};                                            \
  const floatx2 fd_ = one_ + ef_;                                              \
  const floatx2 P1_ = (one_ + ei_) * (one_ + eg_);                             \
  const floatx2 Dp_ = P1_ * fd_;                                               \
  const floatx2 R_  = {rcpf(Dp_.x), rcpf(Dp_.y)};                              \
  const floatx2 T_  = (sgn2_ * eg_ + sgp2_) * fd_;                             \
  (CS2) = ((CS2) * P1_ + T_) * R_;                                             \
  (CS2) = __builtin_elementwise_min((CS2), (floatx2){60.0f, 60.0f});           \
  const floatx2 ec_ = {ex2((CS2).x), ex2((CS2).y)};                            \
  const floatx2 P2_ = (one_ + eo_) * (one_ + ec_);                             \
  const floatx2 R2_ = {rcpf(P2_.x), rcpf(P2_.y)};                              \
  const floatx2 HOUT = (one_ - ec_) * R2_;

// pack both h (adjacent units) into one b32 LDS write
#define PTAIL(PA, PB, CS2, ZW32, WIDX)                                         \
  do {                                                                         \
    PTAIL_CORE(PA, PB, CS2, hv_)                                               \
    (ZW32)[WIDX] =                                                             \
        __builtin_bit_cast(unsigned, __builtin_amdgcn_cvt_pkrtz(hv_.x, hv_.y)); \
  } while (0)

__global__ __launch_bounds__(NTH)
__attribute__((amdgpu_waves_per_eu(4, 4)))
void lstm2_mfma16(
    const float* __restrict__ x,
    const float* __restrict__ w_ih0, const float* __restrict__ w_hh0,
    const float* __restrict__ b_ih0, const float* __restrict__ b_hh0,
    const float* __restrict__ w_ih1, const float* __restrict__ w_hh1,
    const float* __restrict__ b_ih1, const float* __restrict__ b_hh1,
    float* __restrict__ out)
{
  __shared__ __align__(16) unsigned short Z[2][2048];  // fp16 h: [buf][kt][lane][8]
  __shared__ __align__(16) float xh[TT * 16 * 4];      // x re-laid: [t][b][4] (pad unused)

  const int tid  = threadIdx.x;
  const int lane = tid & 63;
  const int wv   = tid >> 6;
  const int n15  = lane & 15;
  const int quad = lane >> 4;
  const int bbase = blockIdx.x * NB;
  const float sA = ((n15 & 3) == 2) ? SGP : SS_;

  // stage x -> [t][b][4] layout (coalesced global reads, scattered LDS writes)
  {
    const float* xg = x + (size_t)bbase * (TT * 3);
    for (int i = tid; i < XLEN; i += NTH) {
      const int b = i / 1095;
      const int rem = i - b * 1095;
      const int t = rem / 3;
      const int c = rem - 3 * t;
      xh[(t * 16 + b) * 4 + c] = xg[i];
    }
    for (int i = tid; i < 2048; i += NTH) { Z[0][i] = 0; Z[1][i] = 0; }
  }
  unsigned short* const Zb0 = &Z[0][0];
  unsigned short* const Zb1 = &Z[1][0];
  __syncthreads();   // barrier #1

  // Adjacent-unit retiling: wave w, tile A -> units 8w+2q (q=quad), tile B -> +1.
  // Thread's two h values are units j0=8w+2q, j1=j0+1 -> one packed b32 write.

  if (wv < 8) {
    // ================= E role: layer-2 GEMM + combine2 =================
    const int w = wv;
    halfx8 a2[2][4];
    floatx4 b1v[2];
    #pragma unroll
    for (int tt = 0; tt < 2; ++tt) {
      const int arow = (n15 & 3) * 64 + 8 * w + 2 * (n15 >> 2) + tt;
      #pragma unroll
      for (int kt = 0; kt < 4; ++kt) {
        const int k0 = kt * 32 + quad * 8;
        const float* src = (k0 < 64) ? (w_ih1 + arow * 64 + k0)
                                     : (w_hh1 + arow * 64 + (k0 - 64));
        LOADFRAG(src, sA, a2[tt][kt]);
      }
      #pragma unroll
      for (int r = 0; r < 4; ++r) {
        const int crow = r * 64 + 8 * w + 2 * quad + tt;
        const float sC = (r == 2) ? SGP : SS_;
        b1v[tt][r] = sC * (b_ih1[crow] + b_hh1[crow]);
      }
    }
    const int j0 = 8 * w + 2 * quad;
    const int widx = 512 + (w >> 2) * 256 + (w & 3) * 64 + n15 * 4 + quad;
    floatx2 c2v = {0.f, 0.f};
    const floatx4 zf_ = {0.f, 0.f, 0.f, 0.f};
    const halfx8* const Z0r = (const halfx8*)Zb0 + lane;
    const halfx8* const Z1r = (const halfx8*)Zb1 + lane;

    __syncthreads();   // barrier #2 (matches D prologue barrier)

    // 2+2 split accumulation chains: halves MFMA dep depth (4 -> 2) per step
#define EMM(E0, E1, BH0, BH1, BH2, BH3)                                        \
      floatx4 E0, E1;                                                          \
      {                                                                        \
        __builtin_amdgcn_s_setprio(1);                                         \
        floatx4 ea = MMH(a2[0][0], BH0, b1v[0]);                               \
        floatx4 fa = MMH(a2[0][2], BH2, zf_);                                  \
        floatx4 eb = MMH(a2[1][0], BH0, b1v[1]);                               \
        floatx4 fb = MMH(a2[1][2], BH2, zf_);                                  \
        ea = MMH(a2[0][1], BH1, ea);                                           \
        fa = MMH(a2[0][3], BH3, fa);                                           \
        eb = MMH(a2[1][1], BH1, eb);                                           \
        fb = MMH(a2[1][3], BH3, fb);                                           \
        __builtin_amdgcn_s_setprio(0);                                         \
        E0 = ea + fa;                                                          \
        E1 = eb + fb;                                                          \
      }

#define ESTEP(ZRP, ZW32)                                                       \
    do {                                                                       \
      const halfx8 bh0 = (ZRP)[0],   bh1 = (ZRP)[64];                          \
      const halfx8 bh2 = (ZRP)[128], bh3 = (ZRP)[192];                         \
      EMM(e0, e1, bh0, bh1, bh2, bh3)                                          \
      PTAIL(e0, e1, c2v, ZW32, widx);                                          \
      __syncthreads();                                                         \
    } while (0)

    for (int it = 0; it < 182; ++it) {
      ESTEP(Z0r, (unsigned*)Zb1);
      ESTEP(Z1r, (unsigned*)Zb0);
    }

    // peel t=364: gates2 -> h2(364) -> out (units j0, j0+1 adjacent)
    {
      const halfx8 bh0 = Z0r[0],   bh1 = Z0r[64];
      const halfx8 bh2 = Z0r[128], bh3 = Z0r[192];
      EMM(e0, e1, bh0, bh1, bh2, bh3)
      PTAIL_CORE(e0, e1, c2v, hv_)
      *(floatx2*)(out + (size_t)(bbase + n15) * 64 + j0) = hv_;
    }
  } else {
    // ================= D role: layer-1 GEMM + combine1 =================
    const int u = wv - 8;
    halfx8 a1[2][2];
    floatx4 wiX[2], wiY[2], wiZ[2], b0v[2];
    #pragma unroll
    for (int tt = 0; tt < 2; ++tt) {
      const int arow = (n15 & 3) * 64 + 8 * u + 2 * (n15 >> 2) + tt;
      #pragma unroll
      for (int kt = 0; kt < 2; ++kt) {
        const float* src = w_hh0 + arow * 64 + kt * 32 + quad * 8;
        LOADFRAG(src, sA, a1[tt][kt]);
      }
      #pragma unroll
      for (int r = 0; r < 4; ++r) {
        const int crow = r * 64 + 8 * u + 2 * quad + tt;
        const float sC = (r == 2) ? SGP : SS_;
        wiX[tt][r] = sC * w_ih0[crow * 3 + 0];
        wiY[tt][r] = sC * w_ih0[crow * 3 + 1];
        wiZ[tt][r] = sC * w_ih0[crow * 3 + 2];
        b0v[tt][r] = sC * (b_ih0[crow] + b_hh0[crow]);
      }
    }
    const int widx = (u >> 2) * 256 + (u & 3) * 64 + n15 * 4 + quad;  // h1 region
    floatx2 c1v = {0.f, 0.f};
    const halfx8* const Z0r = (const halfx8*)Zb0 + lane;
    const halfx8* const Z1r = (const halfx8*)Zb1 + lane;

    // prologue: h1(0) from x(0) only -> Zb0
    {
      const floatx4 xv = *(const floatx4*)(xh + n15 * 4);
      const floatx4 s0 = {xv[0], xv[0], xv[0], xv[0]};
      const floatx4 s1 = {xv[1], xv[1], xv[1], xv[1]};
      const floatx4 s2 = {xv[2], xv[2], xv[2], xv[2]};
      floatx4 d0 = __builtin_elementwise_fma(wiX[0], s0,
                     __builtin_elementwise_fma(wiY[0], s1,
                       __builtin_elementwise_fma(wiZ[0], s2, b0v[0])));
      floatx4 d1 = __builtin_elementwise_fma(wiX[1], s0,
                     __builtin_elementwise_fma(wiY[1], s1,
                       __builtin_elementwise_fma(wiZ[1], s2, b0v[1])));
      PTAIL(d0, d1, c1v, (unsigned*)Zb0, widx);   // c1v=0 -> f-term vanishes
    }
    __syncthreads();   // barrier #2

    const float* xp = xh + 64 + n15 * 4;   // x(t+1), one b128 per step

#define DSTEP(ZRP, ZW32)                                                       \
    do {                                                                       \
      const halfx8 bh0 = (ZRP)[0], bh1 = (ZRP)[64];                            \
      const floatx4 xv = *(const floatx4*)xp;                                  \
      const floatx4 s0 = {xv[0], xv[0], xv[0], xv[0]};                         \
      const floatx4 s1 = {xv[1], xv[1], xv[1], xv[1]};                         \
      const floatx4 s2 = {xv[2], xv[2], xv[2], xv[2]};                         \
      floatx4 d0 = __builtin_elementwise_fma(wiX[0], s0,                       \
                     __builtin_elementwise_fma(wiY[0], s1,                     \
                       __builtin_elementwise_fma(wiZ[0], s2, b0v[0])));        \
      floatx4 d1 = __builtin_elementwise_fma(wiX[1], s0,                       \
                     __builtin_elementwise_fma(wiY[1], s1,                     \
                       __builtin_elementwise_fma(wiZ[1], s2, b0v[1])));        \
      __builtin_amdgcn_s_setprio(1);                                           \
      d0 = MMH(a1[0][0], bh0, d0); d0 = MMH(a1[0][1], bh1, d0);                \
      d1 = MMH(a1[1][0], bh0, d1); d1 = MMH(a1[1][1], bh1, d1);                \
      __builtin_amdgcn_s_setprio(0);                                           \
      PTAIL(d0, d1, c1v, ZW32, widx);                                          \
      xp += 64;                                                                \
      __syncthreads();                                                         \
    } while (0)

    for (int it = 0; it < 182; ++it) {
      DSTEP(Z0r, (unsigned*)Zb1);
      DSTEP(Z1r, (unsigned*)Zb0);
    }
    // peel t=364: nothing for D
  }
}

extern "C" void kernel_launch(void* const* d_in, const int* in_sizes, int n_in,
                              void* d_out, int out_size, void* d_ws, size_t ws_size,
                              hipStream_t stream) {
  const float* x     = (const float*)d_in[0];
  const float* w_ih0 = (const float*)d_in[1];
  const float* w_hh0 = (const float*)d_in[2];
  const float* b_ih0 = (const float*)d_in[3];
  const float* b_hh0 = (const float*)d_in[4];
  const float* w_ih1 = (const float*)d_in[5];
  const float* w_hh1 = (const float*)d_in[6];
  const float* b_ih1 = (const float*)d_in[7];
  const float* b_hh1 = (const float*)d_in[8];
  float* out = (float*)d_out;

  const int B = in_sizes[0] / (TT * 3);   // 4096
  const int grid = B / NB;                // 256 blocks -> 1 per CU

  lstm2_mfma16<<<dim3(grid), dim3(NTH), 0, stream>>>(
      x, w_ih0, w_hh0, b_ih0, b_hh0, w_ih1, w_hh1, b_ih1, b_hh1, out);
}